// Round 1
// 1941.968 us; speedup vs baseline: 1.0034x; 1.0034x over previous
//
#include <hip/hip_runtime.h>

// subLSTM: T=2048, B=64, I=256, H=256, G=4H=1024.
// R7 = R6 + (1) t+2 xp prefetch moved into the o-part2 MFMA latency shadow
// (replaces dead NOPTAIL nops; removes ~20cy from the all-wave serial tail),
// (2) forget-gate clause split 4+4 so MFMAs start at lgkmcnt(2) instead of
// draining all four bq ds_reads, (3) s_setprio 1/0 around every MFMA clause
// so MFMA-ready waves win issue arbitration over sigmoid-phase waves.

typedef __attribute__((ext_vector_type(4))) float f32x4;
typedef __attribute__((ext_vector_type(8))) short bf16x8;
typedef __attribute__((ext_vector_type(4))) int i32x4;
typedef __attribute__((ext_vector_type(4))) unsigned short u16x4;

constexpr float WSCALE = 2032.0f;                 // 127 / 0.0625
constexpr float SC = 1.0f / (2032.0f * 127.0f);   // dequant

__device__ __forceinline__ unsigned short f2bf(float f) {
  unsigned u = __builtin_bit_cast(unsigned, f);
  u += 0x7fffu + ((u >> 16) & 1u);
  return (unsigned short)(u >> 16);
}
__device__ __forceinline__ float sigmf(float x) {
  return __builtin_amdgcn_rcpf(1.0f + __expf(-x));
}

// ---------------- W_h -> int8 ----------------
__global__ void quantw_kernel(const float* __restrict__ Wh,
                              signed char* __restrict__ Wq) {
  int i = blockIdx.x * 256 + threadIdx.x;
  float q = rintf(Wh[i] * WSCALE);
  q = fminf(127.0f, fmaxf(-127.0f, q));
  Wq[i] = (signed char)(int)q;
}

// ---------------- xproj GEMM body (proven 256-thr code; waves 4-7 idle
// but hit uniform __syncthreads) ----------------
__device__ __forceinline__ void gemm_body(char* smem, int gb,
                                          const float* __restrict__ x,
                                          const float* __restrict__ Wi,
                                          const float* __restrict__ bi,
                                          const float* __restrict__ bh,
                                          float* __restrict__ xpOut, long m0) {
  typedef unsigned short row72[72];
  row72* Al = (row72*)smem;
  row72* Bl = (row72*)(smem + 18432);
  const int tid = threadIdx.x;
  const int act = tid < 256;
  const int lane = tid & 63, wv = (tid >> 6) & 3;
  const int wm = wv >> 1, wn = wv & 1, cl = lane & 15, cg = lane >> 4;
  const int bx = gb >> 3, by = gb & 7;
  const long gm0 = m0 + (long)bx * 128;
  const int lm0 = bx * 128;
  const int n0 = by * 128;
  const int srow = (tid & 255) >> 1, sh = (tid & 1) * 32;

  f32x4 acc[4][4];
#pragma unroll
  for (int m = 0; m < 4; ++m)
#pragma unroll
    for (int n = 0; n < 4; ++n) acc[m][n] = (f32x4){0.f, 0.f, 0.f, 0.f};

  for (int kt = 0; kt < 4; ++kt) {
    if (act) {
      const float* pa = x + (gm0 + srow) * 256 + kt * 64 + sh;
      const float* pb = Wi + (long)(n0 + srow) * 256 + kt * 64 + sh;
#pragma unroll
      for (int j = 0; j < 8; ++j) {
        f32x4 va = *(const f32x4*)(pa + j * 4);
        f32x4 vb = *(const f32x4*)(pb + j * 4);
        u16x4 ua, ub;
#pragma unroll
        for (int k = 0; k < 4; ++k) { ua[k] = f2bf(va[k]); ub[k] = f2bf(vb[k]); }
        *(u16x4*)&Al[srow][sh + j * 4] = ua;
        *(u16x4*)&Bl[srow][sh + j * 4] = ub;
      }
    }
    __syncthreads();
    if (act) {
#pragma unroll
      for (int ks = 0; ks < 2; ++ks) {
        bf16x8 af[4], bfv[4];
#pragma unroll
        for (int m = 0; m < 4; ++m)
          af[m] = *(const bf16x8*)&Al[wm * 64 + m * 16 + cl][ks * 32 + cg * 8];
#pragma unroll
        for (int n = 0; n < 4; ++n)
          bfv[n] = *(const bf16x8*)&Bl[wn * 64 + n * 16 + cl][ks * 32 + cg * 8];
#pragma unroll
        for (int m = 0; m < 4; ++m)
#pragma unroll
          for (int n = 0; n < 4; ++n)
            acc[m][n] = __builtin_amdgcn_mfma_f32_16x16x32_bf16(
                af[m], bfv[n], acc[m][n], 0, 0, 0);
      }
    }
    __syncthreads();
  }
  if (act) {
#pragma unroll
    for (int n = 0; n < 4; ++n) {
      int gn = n0 + wn * 64 + n * 16 + cl;
      float bias = bi[gn] + bh[gn];
#pragma unroll
      for (int m = 0; m < 4; ++m) {
        int lrow = lm0 + wm * 64 + m * 16 + cg * 4;
#pragma unroll
        for (int r = 0; r < 4; ++r)
          xpOut[(long)(lrow + r) * 1024 + gn] = acc[m][n][r] + bias;
      }
    }
  }
}

// ---------------- recurrent body ----------------
#define SB() __builtin_amdgcn_sched_barrier(0)

#define RAW_BARRIER()                                         \
  do {                                                        \
    __builtin_amdgcn_sched_barrier(0);                        \
    asm volatile("s_waitcnt lgkmcnt(0)" ::: "memory");        \
    __builtin_amdgcn_s_barrier();                             \
    asm volatile("" ::: "memory");                            \
    __builtin_amdgcn_sched_barrier(0);                        \
  } while (0)

#define MFMA_TG(A0_, A1_, tg, TAIL)                                           \
  asm volatile("s_setprio 1\n\t"                                              \
               "s_nop 3\n\t"                                                  \
               "v_mfma_i32_16x16x64_i8 %0, %2, %10, %0\n\t"                   \
               "v_mfma_i32_16x16x64_i8 %1, %3, %10, %1\n\t"                   \
               "v_mfma_i32_16x16x64_i8 %0, %4, %11, %0\n\t"                   \
               "v_mfma_i32_16x16x64_i8 %1, %5, %11, %1\n\t"                   \
               "v_mfma_i32_16x16x64_i8 %0, %6, %12, %0\n\t"                   \
               "v_mfma_i32_16x16x64_i8 %1, %7, %12, %1\n\t"                   \
               "v_mfma_i32_16x16x64_i8 %0, %8, %13, %0\n\t"                   \
               "v_mfma_i32_16x16x64_i8 %1, %9, %13, %1\n\t"                   \
               "s_setprio 0\n\t" TAIL                                         \
               : "+v"(A0_), "+v"(A1_)                                         \
               : "a"(wf[tg][0][0]), "a"(wf[tg][1][0]), "a"(wf[tg][0][1]),     \
                 "a"(wf[tg][1][1]), "a"(wf[tg][0][2]), "a"(wf[tg][1][2]),     \
                 "a"(wf[tg][0][3]), "a"(wf[tg][1][3]), "v"(bq0), "v"(bq1),    \
                 "v"(bq2), "v"(bq3))

#define MFMA_TG4(A0_, A1_, tg, QA, QB, BQA, BQB, TAIL)                        \
  asm volatile("s_setprio 1\n\t"                                              \
               "s_nop 3\n\t"                                                  \
               "v_mfma_i32_16x16x64_i8 %0, %2, %6, %0\n\t"                    \
               "v_mfma_i32_16x16x64_i8 %1, %3, %6, %1\n\t"                    \
               "v_mfma_i32_16x16x64_i8 %0, %4, %7, %0\n\t"                    \
               "v_mfma_i32_16x16x64_i8 %1, %5, %7, %1\n\t"                    \
               "s_setprio 0\n\t" TAIL                                         \
               : "+v"(A0_), "+v"(A1_)                                         \
               : "a"(wf[tg][0][QA]), "a"(wf[tg][1][QA]),                      \
                 "a"(wf[tg][0][QB]), "a"(wf[tg][1][QB]), "v"(BQA), "v"(BQB))

#define NOTAIL ""
#define HALFNOP "s_nop 7\n\ts_nop 7\n\t"

// select reg (cl&3) of chain ((cl>>2)&1) -- 7 cndmasks, masks loop-invariant
#define SEL8(A0_, A1_)                      \
  ({                                        \
    int t0_ = bs_ ? (A1_)[0] : (A0_)[0];    \
    int t1_ = bs_ ? (A1_)[1] : (A0_)[1];    \
    int t2_ = bs_ ? (A1_)[2] : (A0_)[2];    \
    int t3_ = bs_ ? (A1_)[3] : (A0_)[3];    \
    int lo_ = br0_ ? t1_ : t0_;             \
    int hi_ = br0_ ? t3_ : t2_;             \
    br1_ ? hi_ : lo_;                       \
  })

// gate blocks f,z,i then o split 4+4; the gi/c chain hides under o-part1/2,
// and the t+2 prefetch now hides in o-part2's MFMA latency shadow instead of
// sitting on the serial tail. Each VALU clause is sched_barrier-bounded.
#define STEP(TT, XBUF)                                                         \
  do {                                                                         \
    const int rs = (TT) & 1;                                                   \
    i32x4 bq0 = *(const i32x4*)((const char*)(&hq[rs][0]) + 0 + cg * 16);      \
    i32x4 bq1 = *(const i32x4*)((const char*)(&hq[rs][0]) + 64 + cg * 16);     \
    i32x4 bq2 = *(const i32x4*)((const char*)(&hq[rs][0]) + 128 + cg * 16);    \
    i32x4 bq3 = *(const i32x4*)((const char*)(&hq[rs][0]) + 192 + cg * 16);    \
    i32x4 a00 = {0, 0, 0, 0}, a01 = {0, 0, 0, 0};                              \
    i32x4 a10 = {0, 0, 0, 0}, a11 = {0, 0, 0, 0};                              \
    i32x4 a20 = {0, 0, 0, 0}, a21 = {0, 0, 0, 0};                              \
    i32x4 a30 = {0, 0, 0, 0}, a31 = {0, 0, 0, 0};                              \
    MFMA_TG4(a30, a31, 3, 0, 1, bq0, bq1, NOTAIL); /* forget q0,q1 */          \
    MFMA_TG4(a30, a31, 3, 2, 3, bq2, bq3, NOTAIL); /* forget q2,q3 */          \
    MFMA_TG(a20, a21, 2, NOTAIL); /* z      */                                 \
    SB();                                                                      \
    float gf = sigmf(XBUF[3] + SC * (float)SEL8(a30, a31));                    \
    SB();                                                                      \
    MFMA_TG(a00, a01, 0, NOTAIL); /* in     */                                 \
    SB();                                                                      \
    float gz = sigmf(XBUF[2] + SC * (float)SEL8(a20, a21));                    \
    SB();                                                                      \
    MFMA_TG4(a10, a11, 1, 0, 1, bq0, bq1, NOTAIL); /* out q0,q1 */             \
    SB();                                                                      \
    float gi = sigmf(XBUF[0] + SC * (float)SEL8(a00, a01));                    \
    c_own = c_own * gf + gz - gi;                                              \
    float sc_ = sigmf(c_own);                                                  \
    float x1s_ = XBUF[1];                                                      \
    SB();                                                                      \
    MFMA_TG4(a10, a11, 1, 2, 3, bq2, bq3, HALFNOP); /* out q2,q3 */            \
    SB();                                                                      \
    if ((TT) + 2 < nt) { /* prefetch fills the o-part2 latency shadow */       \
      _Pragma("unroll") for (int tg = 0; tg < 4; ++tg)                         \
          XBUF[tg] = xp[((long)((TT) + 2) * 64 + b) * 1024 + tg * 256 + u];    \
    } else {                                                                   \
      asm volatile("s_nop 7\n\ts_nop 7");                                      \
    }                                                                          \
    SB();                                                                      \
    float go = sigmf(x1s_ + SC * (float)SEL8(a10, a11));                       \
    float hv = sc_ - go;                                                       \
    int qv = (int)rintf(hv * 127.0f);                                          \
    if (cl < 8) {                                                              \
      ((signed char*)(&hq[rs ^ 1][0]))[u] = (signed char)qv;                   \
      out[((long)(t0 + (TT)) * 64 + b) * 256 + u] = hv;                        \
      if (last && (TT) == nt - 1) {                                            \
        out[33554432L + b * 256 + u] = hv;                                     \
        out[33554432L + 16384L + b * 256 + u] = c_own;                         \
      }                                                                        \
    }                                                                          \
    RAW_BARRIER();                                                             \
  } while (0)

__device__ __forceinline__ void recur_body(
    char* smem, const float* __restrict__ xp, float* __restrict__ out,
    float* __restrict__ cst, int* __restrict__ hqst,
    const float* __restrict__ h0, const float* __restrict__ c0,
    const signed char* __restrict__ Wq, int t0, int nt, int first, int last) {
  const int b = blockIdx.x, tid = threadIdx.x;
  const int w = tid >> 6, lane = tid & 63, cl = lane & 15, cg = lane >> 4;
  const int bs_ = (cl >> 2) & 1;   // my s-chain
  const int br0_ = cl & 1;         // my reg r bit0
  const int br1_ = (cl >> 1) & 1;  // my reg r bit1
  const int u = w * 32 + bs_ * 16 + cg * 4 + (cl & 3);  // my ONE unit
  int(*hq)[64] = (int(*)[64])smem;  // int8 h, double-buffered (2x256B)

  // W_h fragments: rows tg*256 + w*32 + s*16 + cl, K chunk q*64 + cg*16.
  // Every use is via an "a" asm constraint -> pinned in 128 AGPRs.
  i32x4 wf[4][2][4];
#pragma unroll
  for (int tg = 0; tg < 4; ++tg)
#pragma unroll
    for (int s = 0; s < 2; ++s)
#pragma unroll
      for (int q = 0; q < 4; ++q)
        wf[tg][s][q] = *(const i32x4*)(Wq +
                                       (tg * 256 + w * 32 + s * 16 + cl) * 256 +
                                       q * 64 + cg * 16);

  float c_own = first ? c0[b * 256 + u] : cst[b * 256 + u];

  if (tid < 64) {
    int word;
    if (first) {
      int qj[4];
#pragma unroll
      for (int j = 0; j < 4; ++j) {
        float v = h0[b * 256 + tid * 4 + j];
        qj[j] = (int)rintf(fminf(1.0f, fmaxf(-1.0f, v)) * 127.0f);
      }
      word = (qj[0] & 255) | ((qj[1] & 255) << 8) | ((qj[2] & 255) << 16) |
             ((qj[3] & 255) << 24);
    } else {
      word = hqst[b * 64 + tid];
    }
    hq[0][tid] = word;
  }

  float xa[4], xb[4];
#pragma unroll
  for (int tg = 0; tg < 4; ++tg) {
    xa[tg] = xp[((long)0 * 64 + b) * 1024 + tg * 256 + u];
    xb[tg] = xp[((long)1 * 64 + b) * 1024 + tg * 256 + u];
  }
  __syncthreads();

  for (int t = 0; t < nt; t += 2) {
    STEP(t, xa);
    STEP(t + 1, xb);
  }

  if (cl < 8) cst[b * 256 + u] = c_own;
  if (tid < 64) hqst[b * 64 + tid] = hq[0][tid];
}

// ---------------- fused kernel ----------------
// blocks 0..63: recur chunk c-1.  blocks 64+: gemm chunk c.
// 82KB static smem -> hard 1 block/CU: gemm never co-resides with recur.
__global__ __launch_bounds__(512, 1) void fused_kernel(
    const float* __restrict__ x, const float* __restrict__ Wi,
    const float* __restrict__ bi, const float* __restrict__ bh,
    float* __restrict__ gslot, long m0, int have_gemm,
    const float* __restrict__ rslot, float* __restrict__ out,
    float* __restrict__ cst, int* __restrict__ hqst,
    const float* __restrict__ h0, const float* __restrict__ c0,
    const signed char* __restrict__ Wq, int t0, int nt, int first, int last,
    int have_recur) {
  __shared__ __align__(16) char smem[83968];
  if (blockIdx.x < 64) {
    if (have_recur)
      recur_body(smem, rslot, out, cst, hqst, h0, c0, Wq, t0, nt, first, last);
  } else {
    if (have_gemm) gemm_body(smem, blockIdx.x - 64, x, Wi, bi, bh, gslot, m0);
  }
}

// ---------------- host ----------------
extern "C" void kernel_launch(void* const* d_in, const int* in_sizes, int n_in,
                              void* d_out, int out_size, void* d_ws,
                              size_t ws_size, hipStream_t stream) {
  const float* x = (const float*)d_in[0];
  const float* h0 = (const float*)d_in[1];
  const float* c0 = (const float*)d_in[2];
  const float* Wi = (const float*)d_in[3];
  const float* Wh = (const float*)d_in[4];
  const float* bi = (const float*)d_in[5];
  const float* bh = (const float*)d_in[6];
  float* out = (float*)d_out;

  const size_t fixed = 262144 /*Wq*/ + 65536 /*c*/ + 16384 /*hq*/;
  int chunkT = 32;
  const int cands[4] = {256, 128, 64, 32};
  for (int i = 0; i < 4; ++i) {
    size_t slot = (size_t)cands[i] * 64 * 1024 * 4;  // fp32 bytes per slot
    if (fixed + 2 * slot <= ws_size) { chunkT = cands[i]; break; }
  }

  char* p = (char*)d_ws;
  signed char* Wq = (signed char*)p;  p += 262144;
  float* cst = (float*)p;             p += 65536;
  int* hqst = (int*)p;                p += 16384;
  float* ring = (float*)p;
  const size_t slotElems = (size_t)chunkT * 64 * 1024;

  quantw_kernel<<<1024, 256, 0, stream>>>(Wh, Wq);

  const int nchunks = 2048 / chunkT;
  for (int c = 0; c <= nchunks; ++c) {
    const int hg = (c < nchunks) ? 1 : 0;
    const int hr = (c > 0) ? 1 : 0;
    float* gs = ring + (size_t)(c & 1) * slotElems;
    const float* rs = ring + (size_t)((c ^ 1) & 1) * slotElems;
    const int ngb = hg ? (chunkT / 2) * 8 : 0;
    fused_kernel<<<64 + ngb, 512, 0, stream>>>(
        x, Wi, bi, bh, gs, (long)c * chunkT * 64, hg, rs, out, cst, hqst, h0,
        c0, Wq, (c - 1) * chunkT, chunkT, (c == 1) ? 1 : 0,
        (c == nchunks) ? 1 : 0, hr);
  }
}

// Round 2
// 1922.496 us; speedup vs baseline: 1.0135x; 1.0101x over previous
//
#include <hip/hip_runtime.h>

// subLSTM: T=2048, B=64, I=256, H=256, G=4H=1024.
// R8 = R7 + software wave-stagger: the two waves sharing each SIMD get
// COMPLEMENTARY clause schedules (even group = R7 order M16/V/M8/V/M4/V/M4/V;
// odd group = M24/V/M8/V...) so one wave's VALU clause lands in the other
// wave's MFMA-issue window instead of lockstep phase-alignment. Group bit
// (w ^ (w>>2)) & 1 gives opposite groups per SIMD under both w%4 and w>>1
// wave->SIMD mappings. Same math, same per-wave work, same barrier count.

typedef __attribute__((ext_vector_type(4))) float f32x4;
typedef __attribute__((ext_vector_type(8))) short bf16x8;
typedef __attribute__((ext_vector_type(4))) int i32x4;
typedef __attribute__((ext_vector_type(4))) unsigned short u16x4;

constexpr float WSCALE = 2032.0f;                 // 127 / 0.0625
constexpr float SC = 1.0f / (2032.0f * 127.0f);   // dequant

__device__ __forceinline__ unsigned short f2bf(float f) {
  unsigned u = __builtin_bit_cast(unsigned, f);
  u += 0x7fffu + ((u >> 16) & 1u);
  return (unsigned short)(u >> 16);
}
__device__ __forceinline__ float sigmf(float x) {
  return __builtin_amdgcn_rcpf(1.0f + __expf(-x));
}

// ---------------- W_h -> int8 ----------------
__global__ void quantw_kernel(const float* __restrict__ Wh,
                              signed char* __restrict__ Wq) {
  int i = blockIdx.x * 256 + threadIdx.x;
  float q = rintf(Wh[i] * WSCALE);
  q = fminf(127.0f, fmaxf(-127.0f, q));
  Wq[i] = (signed char)(int)q;
}

// ---------------- xproj GEMM body (proven 256-thr code; waves 4-7 idle
// but hit uniform __syncthreads) ----------------
__device__ __forceinline__ void gemm_body(char* smem, int gb,
                                          const float* __restrict__ x,
                                          const float* __restrict__ Wi,
                                          const float* __restrict__ bi,
                                          const float* __restrict__ bh,
                                          float* __restrict__ xpOut, long m0) {
  typedef unsigned short row72[72];
  row72* Al = (row72*)smem;
  row72* Bl = (row72*)(smem + 18432);
  const int tid = threadIdx.x;
  const int act = tid < 256;
  const int lane = tid & 63, wv = (tid >> 6) & 3;
  const int wm = wv >> 1, wn = wv & 1, cl = lane & 15, cg = lane >> 4;
  const int bx = gb >> 3, by = gb & 7;
  const long gm0 = m0 + (long)bx * 128;
  const int lm0 = bx * 128;
  const int n0 = by * 128;
  const int srow = (tid & 255) >> 1, sh = (tid & 1) * 32;

  f32x4 acc[4][4];
#pragma unroll
  for (int m = 0; m < 4; ++m)
#pragma unroll
    for (int n = 0; n < 4; ++n) acc[m][n] = (f32x4){0.f, 0.f, 0.f, 0.f};

  for (int kt = 0; kt < 4; ++kt) {
    if (act) {
      const float* pa = x + (gm0 + srow) * 256 + kt * 64 + sh;
      const float* pb = Wi + (long)(n0 + srow) * 256 + kt * 64 + sh;
#pragma unroll
      for (int j = 0; j < 8; ++j) {
        f32x4 va = *(const f32x4*)(pa + j * 4);
        f32x4 vb = *(const f32x4*)(pb + j * 4);
        u16x4 ua, ub;
#pragma unroll
        for (int k = 0; k < 4; ++k) { ua[k] = f2bf(va[k]); ub[k] = f2bf(vb[k]); }
        *(u16x4*)&Al[srow][sh + j * 4] = ua;
        *(u16x4*)&Bl[srow][sh + j * 4] = ub;
      }
    }
    __syncthreads();
    if (act) {
#pragma unroll
      for (int ks = 0; ks < 2; ++ks) {
        bf16x8 af[4], bfv[4];
#pragma unroll
        for (int m = 0; m < 4; ++m)
          af[m] = *(const bf16x8*)&Al[wm * 64 + m * 16 + cl][ks * 32 + cg * 8];
#pragma unroll
        for (int n = 0; n < 4; ++n)
          bfv[n] = *(const bf16x8*)&Bl[wn * 64 + n * 16 + cl][ks * 32 + cg * 8];
#pragma unroll
        for (int m = 0; m < 4; ++m)
#pragma unroll
          for (int n = 0; n < 4; ++n)
            acc[m][n] = __builtin_amdgcn_mfma_f32_16x16x32_bf16(
                af[m], bfv[n], acc[m][n], 0, 0, 0);
      }
    }
    __syncthreads();
  }
  if (act) {
#pragma unroll
    for (int n = 0; n < 4; ++n) {
      int gn = n0 + wn * 64 + n * 16 + cl;
      float bias = bi[gn] + bh[gn];
#pragma unroll
      for (int m = 0; m < 4; ++m) {
        int lrow = lm0 + wm * 64 + m * 16 + cg * 4;
#pragma unroll
        for (int r = 0; r < 4; ++r)
          xpOut[(long)(lrow + r) * 1024 + gn] = acc[m][n][r] + bias;
      }
    }
  }
}

// ---------------- recurrent body ----------------
#define SB() __builtin_amdgcn_sched_barrier(0)

#define RAW_BARRIER()                                         \
  do {                                                        \
    __builtin_amdgcn_sched_barrier(0);                        \
    asm volatile("s_waitcnt lgkmcnt(0)" ::: "memory");        \
    __builtin_amdgcn_s_barrier();                             \
    asm volatile("" ::: "memory");                            \
    __builtin_amdgcn_sched_barrier(0);                        \
  } while (0)

#define MFMA_TG(A0_, A1_, tg, TAIL)                                           \
  asm volatile("s_setprio 1\n\t"                                              \
               "s_nop 3\n\t"                                                  \
               "v_mfma_i32_16x16x64_i8 %0, %2, %10, %0\n\t"                   \
               "v_mfma_i32_16x16x64_i8 %1, %3, %10, %1\n\t"                   \
               "v_mfma_i32_16x16x64_i8 %0, %4, %11, %0\n\t"                   \
               "v_mfma_i32_16x16x64_i8 %1, %5, %11, %1\n\t"                   \
               "v_mfma_i32_16x16x64_i8 %0, %6, %12, %0\n\t"                   \
               "v_mfma_i32_16x16x64_i8 %1, %7, %12, %1\n\t"                   \
               "v_mfma_i32_16x16x64_i8 %0, %8, %13, %0\n\t"                   \
               "v_mfma_i32_16x16x64_i8 %1, %9, %13, %1\n\t"                   \
               "s_setprio 0\n\t" TAIL                                         \
               : "+v"(A0_), "+v"(A1_)                                         \
               : "a"(wf[tg][0][0]), "a"(wf[tg][1][0]), "a"(wf[tg][0][1]),     \
                 "a"(wf[tg][1][1]), "a"(wf[tg][0][2]), "a"(wf[tg][1][2]),     \
                 "a"(wf[tg][0][3]), "a"(wf[tg][1][3]), "v"(bq0), "v"(bq1),    \
                 "v"(bq2), "v"(bq3))

#define MFMA_TG4(A0_, A1_, tg, QA, QB, BQA, BQB, TAIL)                        \
  asm volatile("s_setprio 1\n\t"                                              \
               "s_nop 3\n\t"                                                  \
               "v_mfma_i32_16x16x64_i8 %0, %2, %6, %0\n\t"                    \
               "v_mfma_i32_16x16x64_i8 %1, %3, %6, %1\n\t"                    \
               "v_mfma_i32_16x16x64_i8 %0, %4, %7, %0\n\t"                    \
               "v_mfma_i32_16x16x64_i8 %1, %5, %7, %1\n\t"                    \
               "s_setprio 0\n\t" TAIL                                         \
               : "+v"(A0_), "+v"(A1_)                                         \
               : "a"(wf[tg][0][QA]), "a"(wf[tg][1][QA]),                      \
                 "a"(wf[tg][0][QB]), "a"(wf[tg][1][QB]), "v"(BQA), "v"(BQB))

#define NOTAIL ""
#define HALFNOP "s_nop 7\n\ts_nop 7\n\t"

// select reg (cl&3) of chain ((cl>>2)&1) -- 7 cndmasks, masks loop-invariant
#define SEL8(A0_, A1_)                      \
  ({                                        \
    int t0_ = bs_ ? (A1_)[0] : (A0_)[0];    \
    int t1_ = bs_ ? (A1_)[1] : (A0_)[1];    \
    int t2_ = bs_ ? (A1_)[2] : (A0_)[2];    \
    int t3_ = bs_ ? (A1_)[3] : (A0_)[3];    \
    int lo_ = br0_ ? t1_ : t0_;             \
    int hi_ = br0_ ? t3_ : t2_;             \
    br1_ ? hi_ : lo_;                       \
  })

#define BQ_AND_ACC(TT)                                                         \
    const int rs = (TT) & 1;                                                   \
    i32x4 bq0 = *(const i32x4*)((const char*)(&hq[rs][0]) + 0 + cg * 16);      \
    i32x4 bq1 = *(const i32x4*)((const char*)(&hq[rs][0]) + 64 + cg * 16);     \
    i32x4 bq2 = *(const i32x4*)((const char*)(&hq[rs][0]) + 128 + cg * 16);    \
    i32x4 bq3 = *(const i32x4*)((const char*)(&hq[rs][0]) + 192 + cg * 16);    \
    i32x4 a00 = {0, 0, 0, 0}, a01 = {0, 0, 0, 0};                              \
    i32x4 a10 = {0, 0, 0, 0}, a11 = {0, 0, 0, 0};                              \
    i32x4 a20 = {0, 0, 0, 0}, a21 = {0, 0, 0, 0};                              \
    i32x4 a30 = {0, 0, 0, 0}, a31 = {0, 0, 0, 0};

#define STEP_TAIL(TT)                                                          \
    float hv = sc_ - go;                                                       \
    int qv = (int)rintf(hv * 127.0f);                                          \
    if (cl < 8) {                                                              \
      ((signed char*)(&hq[rs ^ 1][0]))[u] = (signed char)qv;                   \
      out[((long)(t0 + (TT)) * 64 + b) * 256 + u] = hv;                        \
      if (last && (TT) == nt - 1) {                                            \
        out[33554432L + b * 256 + u] = hv;                                     \
        out[33554432L + 16384L + b * 256 + u] = c_own;                         \
      }                                                                        \
    }                                                                          \
    RAW_BARRIER();

// EVEN-group schedule (R7 proven): M16 | gf | M8 | gz | M4 | gi,c | M4+pf | go
#define STEP_E(TT, XBUF)                                                       \
  do {                                                                         \
    BQ_AND_ACC(TT)                                                             \
    MFMA_TG4(a30, a31, 3, 0, 1, bq0, bq1, NOTAIL); /* forget q0,q1 */          \
    MFMA_TG4(a30, a31, 3, 2, 3, bq2, bq3, NOTAIL); /* forget q2,q3 */          \
    MFMA_TG(a20, a21, 2, NOTAIL); /* z      */                                 \
    SB();                                                                      \
    float gf = sigmf(XBUF[3] + SC * (float)SEL8(a30, a31));                    \
    SB();                                                                      \
    MFMA_TG(a00, a01, 0, NOTAIL); /* in     */                                 \
    SB();                                                                      \
    float gz = sigmf(XBUF[2] + SC * (float)SEL8(a20, a21));                    \
    SB();                                                                      \
    MFMA_TG4(a10, a11, 1, 0, 1, bq0, bq1, NOTAIL); /* out q0,q1 */             \
    SB();                                                                      \
    float gi = sigmf(XBUF[0] + SC * (float)SEL8(a00, a01));                    \
    c_own = c_own * gf + gz - gi;                                              \
    float sc_ = sigmf(c_own);                                                  \
    float x1s_ = XBUF[1];                                                      \
    SB();                                                                      \
    MFMA_TG4(a10, a11, 1, 2, 3, bq2, bq3, HALFNOP); /* out q2,q3 */            \
    SB();                                                                      \
    if ((TT) + 2 < nt) { /* prefetch fills the o-part2 latency shadow */       \
      _Pragma("unroll") for (int tg = 0; tg < 4; ++tg)                         \
          XBUF[tg] = xp[((long)((TT) + 2) * 64 + b) * 1024 + tg * 256 + u];    \
    } else {                                                                   \
      asm volatile("s_nop 7\n\ts_nop 7");                                      \
    }                                                                          \
    SB();                                                                      \
    float go = sigmf(x1s_ + SC * (float)SEL8(a10, a11));                       \
    STEP_TAIL(TT)                                                              \
  } while (0)

// ODD-group schedule (staggered): M24 (f,z,i) | gf | M8 (o) | gz,gi,c | pf | go
// Complementary to STEP_E: its VALU clauses land inside the even wave's MFMA
// windows on the shared SIMD, keeping the matrix pipe fed across the step.
#define STEP_O(TT, XBUF)                                                       \
  do {                                                                         \
    BQ_AND_ACC(TT)                                                             \
    MFMA_TG4(a30, a31, 3, 0, 1, bq0, bq1, NOTAIL); /* forget q0,q1 */          \
    MFMA_TG4(a30, a31, 3, 2, 3, bq2, bq3, NOTAIL); /* forget q2,q3 */          \
    MFMA_TG(a20, a21, 2, NOTAIL); /* z      */                                 \
    MFMA_TG(a00, a01, 0, NOTAIL); /* in     */                                 \
    SB();                                                                      \
    float gf = sigmf(XBUF[3] + SC * (float)SEL8(a30, a31));                    \
    SB();                                                                      \
    MFMA_TG(a10, a11, 1, NOTAIL); /* out, full 8 */                            \
    SB();                                                                      \
    float gz = sigmf(XBUF[2] + SC * (float)SEL8(a20, a21));                    \
    float gi = sigmf(XBUF[0] + SC * (float)SEL8(a00, a01));                    \
    c_own = c_own * gf + gz - gi;                                              \
    float sc_ = sigmf(c_own);                                                  \
    float x1s_ = XBUF[1];                                                      \
    SB();                                                                      \
    if ((TT) + 2 < nt) {                                                       \
      _Pragma("unroll") for (int tg = 0; tg < 4; ++tg)                         \
          XBUF[tg] = xp[((long)((TT) + 2) * 64 + b) * 1024 + tg * 256 + u];    \
    }                                                                          \
    SB();                                                                      \
    float go = sigmf(x1s_ + SC * (float)SEL8(a10, a11));                       \
    STEP_TAIL(TT)                                                              \
  } while (0)

__device__ __forceinline__ void recur_body(
    char* smem, const float* __restrict__ xp, float* __restrict__ out,
    float* __restrict__ cst, int* __restrict__ hqst,
    const float* __restrict__ h0, const float* __restrict__ c0,
    const signed char* __restrict__ Wq, int t0, int nt, int first, int last) {
  const int b = blockIdx.x, tid = threadIdx.x;
  const int w = tid >> 6, lane = tid & 63, cl = lane & 15, cg = lane >> 4;
  const int bs_ = (cl >> 2) & 1;   // my s-chain
  const int br0_ = cl & 1;         // my reg r bit0
  const int br1_ = (cl >> 1) & 1;  // my reg r bit1
  const int u = w * 32 + bs_ * 16 + cg * 4 + (cl & 3);  // my ONE unit
  // stagger group: opposite per SIMD under both w%4 and w>>1 wave->SIMD maps
  const int grp = (w ^ (w >> 2)) & 1;
  int(*hq)[64] = (int(*)[64])smem;  // int8 h, double-buffered (2x256B)

  // W_h fragments: rows tg*256 + w*32 + s*16 + cl, K chunk q*64 + cg*16.
  // Every use is via an "a" asm constraint -> pinned in 128 AGPRs.
  i32x4 wf[4][2][4];
#pragma unroll
  for (int tg = 0; tg < 4; ++tg)
#pragma unroll
    for (int s = 0; s < 2; ++s)
#pragma unroll
      for (int q = 0; q < 4; ++q)
        wf[tg][s][q] = *(const i32x4*)(Wq +
                                       (tg * 256 + w * 32 + s * 16 + cl) * 256 +
                                       q * 64 + cg * 16);

  float c_own = first ? c0[b * 256 + u] : cst[b * 256 + u];

  if (tid < 64) {
    int word;
    if (first) {
      int qj[4];
#pragma unroll
      for (int j = 0; j < 4; ++j) {
        float v = h0[b * 256 + tid * 4 + j];
        qj[j] = (int)rintf(fminf(1.0f, fmaxf(-1.0f, v)) * 127.0f);
      }
      word = (qj[0] & 255) | ((qj[1] & 255) << 8) | ((qj[2] & 255) << 16) |
             ((qj[3] & 255) << 24);
    } else {
      word = hqst[b * 64 + tid];
    }
    hq[0][tid] = word;
  }

  float xa[4], xb[4];
#pragma unroll
  for (int tg = 0; tg < 4; ++tg) {
    xa[tg] = xp[((long)0 * 64 + b) * 1024 + tg * 256 + u];
    xb[tg] = xp[((long)1 * 64 + b) * 1024 + tg * 256 + u];
  }
  __syncthreads();

  if (grp) {
    for (int t = 0; t < nt; t += 2) {
      STEP_O(t, xa);
      STEP_O(t + 1, xb);
    }
  } else {
    for (int t = 0; t < nt; t += 2) {
      STEP_E(t, xa);
      STEP_E(t + 1, xb);
    }
  }

  if (cl < 8) cst[b * 256 + u] = c_own;
  if (tid < 64) hqst[b * 64 + tid] = hq[0][tid];
}

// ---------------- fused kernel ----------------
// blocks 0..63: recur chunk c-1.  blocks 64+: gemm chunk c.
// 82KB static smem -> hard 1 block/CU: gemm never co-resides with recur.
__global__ __launch_bounds__(512, 1) void fused_kernel(
    const float* __restrict__ x, const float* __restrict__ Wi,
    const float* __restrict__ bi, const float* __restrict__ bh,
    float* __restrict__ gslot, long m0, int have_gemm,
    const float* __restrict__ rslot, float* __restrict__ out,
    float* __restrict__ cst, int* __restrict__ hqst,
    const float* __restrict__ h0, const float* __restrict__ c0,
    const signed char* __restrict__ Wq, int t0, int nt, int first, int last,
    int have_recur) {
  __shared__ __align__(16) char smem[83968];
  if (blockIdx.x < 64) {
    if (have_recur)
      recur_body(smem, rslot, out, cst, hqst, h0, c0, Wq, t0, nt, first, last);
  } else {
    if (have_gemm) gemm_body(smem, blockIdx.x - 64, x, Wi, bi, bh, gslot, m0);
  }
}

// ---------------- host ----------------
extern "C" void kernel_launch(void* const* d_in, const int* in_sizes, int n_in,
                              void* d_out, int out_size, void* d_ws,
                              size_t ws_size, hipStream_t stream) {
  const float* x = (const float*)d_in[0];
  const float* h0 = (const float*)d_in[1];
  const float* c0 = (const float*)d_in[2];
  const float* Wi = (const float*)d_in[3];
  const float* Wh = (const float*)d_in[4];
  const float* bi = (const float*)d_in[5];
  const float* bh = (const float*)d_in[6];
  float* out = (float*)d_out;

  const size_t fixed = 262144 /*Wq*/ + 65536 /*c*/ + 16384 /*hq*/;
  int chunkT = 32;
  const int cands[4] = {256, 128, 64, 32};
  for (int i = 0; i < 4; ++i) {
    size_t slot = (size_t)cands[i] * 64 * 1024 * 4;  // fp32 bytes per slot
    if (fixed + 2 * slot <= ws_size) { chunkT = cands[i]; break; }
  }

  char* p = (char*)d_ws;
  signed char* Wq = (signed char*)p;  p += 262144;
  float* cst = (float*)p;             p += 65536;
  int* hqst = (int*)p;                p += 16384;
  float* ring = (float*)p;
  const size_t slotElems = (size_t)chunkT * 64 * 1024;

  quantw_kernel<<<1024, 256, 0, stream>>>(Wh, Wq);

  const int nchunks = 2048 / chunkT;
  for (int c = 0; c <= nchunks; ++c) {
    const int hg = (c < nchunks) ? 1 : 0;
    const int hr = (c > 0) ? 1 : 0;
    float* gs = ring + (size_t)(c & 1) * slotElems;
    const float* rs = ring + (size_t)((c ^ 1) & 1) * slotElems;
    const int ngb = hg ? (chunkT / 2) * 8 : 0;
    fused_kernel<<<64 + ngb, 512, 0, stream>>>(
        x, Wi, bi, bh, gs, (long)c * chunkT * 64, hg, rs, out, cst, hqst, h0,
        c0, Wq, (c - 1) * chunkT, chunkT, (c == 1) ? 1 : 0,
        (c == nchunks) ? 1 : 0, hr);
  }
}

// Round 3
// 1814.081 us; speedup vs baseline: 1.0741x; 1.0598x over previous
//
#include <hip/hip_runtime.h>

// subLSTM: T=2048, B=64, I=256, H=256, G=4H=1024.
// R9: chain-interleaved MFMA blocks. The old 8-MFMA clauses had only 2
// independent accumulator chains (A0/A1) -> same-acc MFMAs ~1 issue apart;
// if MFMA result latency ~40-64cy each clause ran chain-limited (~L/2 per
// MFMA) and each of the 4 dependent sigmoid clauses added a full result-
// latency wait. New step = two 16-MFMA asm blocks with 4 round-robin chains
// each (FZ: F-A0/F-A1/Z-A0/Z-A1; IO: I-A0/I-A1/O-A0/O-A1), then ALL VALU in
// one tail. Same-chain spacing = 4 issue slots; mid-step waits collapse.

typedef __attribute__((ext_vector_type(4))) float f32x4;
typedef __attribute__((ext_vector_type(8))) short bf16x8;
typedef __attribute__((ext_vector_type(4))) int i32x4;
typedef __attribute__((ext_vector_type(4))) unsigned short u16x4;

constexpr float WSCALE = 2032.0f;                 // 127 / 0.0625
constexpr float SC = 1.0f / (2032.0f * 127.0f);   // dequant

__device__ __forceinline__ unsigned short f2bf(float f) {
  unsigned u = __builtin_bit_cast(unsigned, f);
  u += 0x7fffu + ((u >> 16) & 1u);
  return (unsigned short)(u >> 16);
}
__device__ __forceinline__ float sigmf(float x) {
  return __builtin_amdgcn_rcpf(1.0f + __expf(-x));
}

// ---------------- W_h -> int8 ----------------
__global__ void quantw_kernel(const float* __restrict__ Wh,
                              signed char* __restrict__ Wq) {
  int i = blockIdx.x * 256 + threadIdx.x;
  float q = rintf(Wh[i] * WSCALE);
  q = fminf(127.0f, fmaxf(-127.0f, q));
  Wq[i] = (signed char)(int)q;
}

// ---------------- xproj GEMM body (proven 256-thr code; waves 4-7 idle
// but hit uniform __syncthreads) ----------------
__device__ __forceinline__ void gemm_body(char* smem, int gb,
                                          const float* __restrict__ x,
                                          const float* __restrict__ Wi,
                                          const float* __restrict__ bi,
                                          const float* __restrict__ bh,
                                          float* __restrict__ xpOut, long m0) {
  typedef unsigned short row72[72];
  row72* Al = (row72*)smem;
  row72* Bl = (row72*)(smem + 18432);
  const int tid = threadIdx.x;
  const int act = tid < 256;
  const int lane = tid & 63, wv = (tid >> 6) & 3;
  const int wm = wv >> 1, wn = wv & 1, cl = lane & 15, cg = lane >> 4;
  const int bx = gb >> 3, by = gb & 7;
  const long gm0 = m0 + (long)bx * 128;
  const int lm0 = bx * 128;
  const int n0 = by * 128;
  const int srow = (tid & 255) >> 1, sh = (tid & 1) * 32;

  f32x4 acc[4][4];
#pragma unroll
  for (int m = 0; m < 4; ++m)
#pragma unroll
    for (int n = 0; n < 4; ++n) acc[m][n] = (f32x4){0.f, 0.f, 0.f, 0.f};

  for (int kt = 0; kt < 4; ++kt) {
    if (act) {
      const float* pa = x + (gm0 + srow) * 256 + kt * 64 + sh;
      const float* pb = Wi + (long)(n0 + srow) * 256 + kt * 64 + sh;
#pragma unroll
      for (int j = 0; j < 8; ++j) {
        f32x4 va = *(const f32x4*)(pa + j * 4);
        f32x4 vb = *(const f32x4*)(pb + j * 4);
        u16x4 ua, ub;
#pragma unroll
        for (int k = 0; k < 4; ++k) { ua[k] = f2bf(va[k]); ub[k] = f2bf(vb[k]); }
        *(u16x4*)&Al[srow][sh + j * 4] = ua;
        *(u16x4*)&Bl[srow][sh + j * 4] = ub;
      }
    }
    __syncthreads();
    if (act) {
#pragma unroll
      for (int ks = 0; ks < 2; ++ks) {
        bf16x8 af[4], bfv[4];
#pragma unroll
        for (int m = 0; m < 4; ++m)
          af[m] = *(const bf16x8*)&Al[wm * 64 + m * 16 + cl][ks * 32 + cg * 8];
#pragma unroll
        for (int n = 0; n < 4; ++n)
          bfv[n] = *(const bf16x8*)&Bl[wn * 64 + n * 16 + cl][ks * 32 + cg * 8];
#pragma unroll
        for (int m = 0; m < 4; ++m)
#pragma unroll
          for (int n = 0; n < 4; ++n)
            acc[m][n] = __builtin_amdgcn_mfma_f32_16x16x32_bf16(
                af[m], bfv[n], acc[m][n], 0, 0, 0);
      }
    }
    __syncthreads();
  }
  if (act) {
#pragma unroll
    for (int n = 0; n < 4; ++n) {
      int gn = n0 + wn * 64 + n * 16 + cl;
      float bias = bi[gn] + bh[gn];
#pragma unroll
      for (int m = 0; m < 4; ++m) {
        int lrow = lm0 + wm * 64 + m * 16 + cg * 4;
#pragma unroll
        for (int r = 0; r < 4; ++r)
          xpOut[(long)(lrow + r) * 1024 + gn] = acc[m][n][r] + bias;
      }
    }
  }
}

// ---------------- recurrent body ----------------
#define SB() __builtin_amdgcn_sched_barrier(0)

#define RAW_BARRIER()                                         \
  do {                                                        \
    __builtin_amdgcn_sched_barrier(0);                        \
    asm volatile("s_waitcnt lgkmcnt(0)" ::: "memory");        \
    __builtin_amdgcn_s_barrier();                             \
    asm volatile("" ::: "memory");                            \
    __builtin_amdgcn_sched_barrier(0);                        \
  } while (0)

// 16 MFMAs, 4 independent accumulator chains (P-A0, P-A1, Q-A0, Q-A1)
// round-robin across the four K-quarters: same-chain spacing = 4 issue
// slots, so the block is issue-limited, not result-latency-limited.
#define MFMA_PAIR16(P0_, P1_, Q0_, Q1_, TP, TQ)                               \
  asm volatile("s_setprio 1\n\t"                                              \
               "s_nop 3\n\t"                                                  \
               "v_mfma_i32_16x16x64_i8 %0, %4, %20, %0\n\t"                   \
               "v_mfma_i32_16x16x64_i8 %1, %5, %20, %1\n\t"                   \
               "v_mfma_i32_16x16x64_i8 %2, %6, %20, %2\n\t"                   \
               "v_mfma_i32_16x16x64_i8 %3, %7, %20, %3\n\t"                   \
               "v_mfma_i32_16x16x64_i8 %0, %8, %21, %0\n\t"                   \
               "v_mfma_i32_16x16x64_i8 %1, %9, %21, %1\n\t"                   \
               "v_mfma_i32_16x16x64_i8 %2, %10, %21, %2\n\t"                  \
               "v_mfma_i32_16x16x64_i8 %3, %11, %21, %3\n\t"                  \
               "v_mfma_i32_16x16x64_i8 %0, %12, %22, %0\n\t"                  \
               "v_mfma_i32_16x16x64_i8 %1, %13, %22, %1\n\t"                  \
               "v_mfma_i32_16x16x64_i8 %2, %14, %22, %2\n\t"                  \
               "v_mfma_i32_16x16x64_i8 %3, %15, %22, %3\n\t"                  \
               "v_mfma_i32_16x16x64_i8 %0, %16, %23, %0\n\t"                  \
               "v_mfma_i32_16x16x64_i8 %1, %17, %23, %1\n\t"                  \
               "v_mfma_i32_16x16x64_i8 %2, %18, %23, %2\n\t"                  \
               "v_mfma_i32_16x16x64_i8 %3, %19, %23, %3\n\t"                  \
               "s_setprio 0"                                                  \
               : "+v"(P0_), "+v"(P1_), "+v"(Q0_), "+v"(Q1_)                   \
               : "a"(wf[TP][0][0]), "a"(wf[TP][1][0]), "a"(wf[TQ][0][0]),     \
                 "a"(wf[TQ][1][0]), "a"(wf[TP][0][1]), "a"(wf[TP][1][1]),     \
                 "a"(wf[TQ][0][1]), "a"(wf[TQ][1][1]), "a"(wf[TP][0][2]),     \
                 "a"(wf[TP][1][2]), "a"(wf[TQ][0][2]), "a"(wf[TQ][1][2]),     \
                 "a"(wf[TP][0][3]), "a"(wf[TP][1][3]), "a"(wf[TQ][0][3]),     \
                 "a"(wf[TQ][1][3]), "v"(bq0), "v"(bq1), "v"(bq2), "v"(bq3))

// select reg (cl&3) of chain ((cl>>2)&1) -- 7 cndmasks, masks loop-invariant
#define SEL8(A0_, A1_)                      \
  ({                                        \
    int t0_ = bs_ ? (A1_)[0] : (A0_)[0];    \
    int t1_ = bs_ ? (A1_)[1] : (A0_)[1];    \
    int t2_ = bs_ ? (A1_)[2] : (A0_)[2];    \
    int t3_ = bs_ ? (A1_)[3] : (A0_)[3];    \
    int lo_ = br0_ ? t1_ : t0_;             \
    int hi_ = br0_ ? t3_ : t2_;             \
    br1_ ? hi_ : lo_;                       \
  })

#define BQ_AND_ACC(TT)                                                         \
    const int rs = (TT) & 1;                                                   \
    i32x4 bq0 = *(const i32x4*)((const char*)(&hq[rs][0]) + 0 + cg * 16);      \
    i32x4 bq1 = *(const i32x4*)((const char*)(&hq[rs][0]) + 64 + cg * 16);     \
    i32x4 bq2 = *(const i32x4*)((const char*)(&hq[rs][0]) + 128 + cg * 16);    \
    i32x4 bq3 = *(const i32x4*)((const char*)(&hq[rs][0]) + 192 + cg * 16);    \
    i32x4 a00 = {0, 0, 0, 0}, a01 = {0, 0, 0, 0};                              \
    i32x4 a10 = {0, 0, 0, 0}, a11 = {0, 0, 0, 0};                              \
    i32x4 a20 = {0, 0, 0, 0}, a21 = {0, 0, 0, 0};                              \
    i32x4 a30 = {0, 0, 0, 0}, a31 = {0, 0, 0, 0};

#define STEP_TAIL(TT)                                                          \
    float hv = sc_ - go;                                                       \
    int qv = (int)rintf(hv * 127.0f);                                          \
    if (cl < 8) {                                                              \
      ((signed char*)(&hq[rs ^ 1][0]))[u] = (signed char)qv;                   \
      out[((long)(t0 + (TT)) * 64 + b) * 256 + u] = hv;                        \
      if (last && (TT) == nt - 1) {                                            \
        out[33554432L + b * 256 + u] = hv;                                     \
        out[33554432L + 16384L + b * 256 + u] = c_own;                         \
      }                                                                        \
    }                                                                          \
    RAW_BARRIER();

// Step: [FZ 16-MFMA block][IO 16-MFMA block] then one VALU tail.
// F results are >=16 MFMAs old at gf's read; I results ~80cy old at gi's
// read (2 issues + gf/gz clause); O results ~115cy old at go's read
// (gf/gz + gi/c-chain + prefetch in between) -- all beyond MFMA latency.
#define STEP(TT, XBUF)                                                         \
  do {                                                                         \
    BQ_AND_ACC(TT)                                                             \
    MFMA_PAIR16(a30, a31, a20, a21, 3, 2); /* forget + z */                    \
    MFMA_PAIR16(a00, a01, a10, a11, 0, 1); /* in + out   */                    \
    SB();                                                                      \
    float gf = sigmf(XBUF[3] + SC * (float)SEL8(a30, a31));                    \
    float gz = sigmf(XBUF[2] + SC * (float)SEL8(a20, a21));                    \
    SB();                                                                      \
    float gi = sigmf(XBUF[0] + SC * (float)SEL8(a00, a01));                    \
    c_own = c_own * gf + gz - gi;                                              \
    float sc_ = sigmf(c_own);                                                  \
    float x1s_ = XBUF[1];                                                      \
    SB();                                                                      \
    if ((TT) + 2 < nt) { /* prefetch t+2; also spaces go's SEL8 from O */      \
      _Pragma("unroll") for (int tg = 0; tg < 4; ++tg)                         \
          XBUF[tg] = xp[((long)((TT) + 2) * 64 + b) * 1024 + tg * 256 + u];    \
    } else {                                                                   \
      asm volatile("s_nop 7\n\ts_nop 7");                                      \
    }                                                                          \
    SB();                                                                      \
    float go = sigmf(x1s_ + SC * (float)SEL8(a10, a11));                       \
    STEP_TAIL(TT)                                                              \
  } while (0)

__device__ __forceinline__ void recur_body(
    char* smem, const float* __restrict__ xp, float* __restrict__ out,
    float* __restrict__ cst, int* __restrict__ hqst,
    const float* __restrict__ h0, const float* __restrict__ c0,
    const signed char* __restrict__ Wq, int t0, int nt, int first, int last) {
  const int b = blockIdx.x, tid = threadIdx.x;
  const int w = tid >> 6, lane = tid & 63, cl = lane & 15, cg = lane >> 4;
  const int bs_ = (cl >> 2) & 1;   // my s-chain
  const int br0_ = cl & 1;         // my reg r bit0
  const int br1_ = (cl >> 1) & 1;  // my reg r bit1
  const int u = w * 32 + bs_ * 16 + cg * 4 + (cl & 3);  // my ONE unit
  int(*hq)[64] = (int(*)[64])smem;  // int8 h, double-buffered (2x256B)

  // W_h fragments: rows tg*256 + w*32 + s*16 + cl, K chunk q*64 + cg*16.
  // Every use is via an "a" asm constraint -> pinned in 128 AGPRs.
  i32x4 wf[4][2][4];
#pragma unroll
  for (int tg = 0; tg < 4; ++tg)
#pragma unroll
    for (int s = 0; s < 2; ++s)
#pragma unroll
      for (int q = 0; q < 4; ++q)
        wf[tg][s][q] = *(const i32x4*)(Wq +
                                       (tg * 256 + w * 32 + s * 16 + cl) * 256 +
                                       q * 64 + cg * 16);

  float c_own = first ? c0[b * 256 + u] : cst[b * 256 + u];

  if (tid < 64) {
    int word;
    if (first) {
      int qj[4];
#pragma unroll
      for (int j = 0; j < 4; ++j) {
        float v = h0[b * 256 + tid * 4 + j];
        qj[j] = (int)rintf(fminf(1.0f, fmaxf(-1.0f, v)) * 127.0f);
      }
      word = (qj[0] & 255) | ((qj[1] & 255) << 8) | ((qj[2] & 255) << 16) |
             ((qj[3] & 255) << 24);
    } else {
      word = hqst[b * 64 + tid];
    }
    hq[0][tid] = word;
  }

  float xa[4], xb[4];
#pragma unroll
  for (int tg = 0; tg < 4; ++tg) {
    xa[tg] = xp[((long)0 * 64 + b) * 1024 + tg * 256 + u];
    xb[tg] = xp[((long)1 * 64 + b) * 1024 + tg * 256 + u];
  }
  __syncthreads();

  for (int t = 0; t < nt; t += 2) {
    STEP(t, xa);
    STEP(t + 1, xb);
  }

  if (cl < 8) cst[b * 256 + u] = c_own;
  if (tid < 64) hqst[b * 64 + tid] = hq[0][tid];
}

// ---------------- fused kernel ----------------
// blocks 0..63: recur chunk c-1.  blocks 64+: gemm chunk c.
// 82KB static smem -> hard 1 block/CU: gemm never co-resides with recur.
__global__ __launch_bounds__(512, 1) void fused_kernel(
    const float* __restrict__ x, const float* __restrict__ Wi,
    const float* __restrict__ bi, const float* __restrict__ bh,
    float* __restrict__ gslot, long m0, int have_gemm,
    const float* __restrict__ rslot, float* __restrict__ out,
    float* __restrict__ cst, int* __restrict__ hqst,
    const float* __restrict__ h0, const float* __restrict__ c0,
    const signed char* __restrict__ Wq, int t0, int nt, int first, int last,
    int have_recur) {
  __shared__ __align__(16) char smem[83968];
  if (blockIdx.x < 64) {
    if (have_recur)
      recur_body(smem, rslot, out, cst, hqst, h0, c0, Wq, t0, nt, first, last);
  } else {
    if (have_gemm) gemm_body(smem, blockIdx.x - 64, x, Wi, bi, bh, gslot, m0);
  }
}

// ---------------- host ----------------
extern "C" void kernel_launch(void* const* d_in, const int* in_sizes, int n_in,
                              void* d_out, int out_size, void* d_ws,
                              size_t ws_size, hipStream_t stream) {
  const float* x = (const float*)d_in[0];
  const float* h0 = (const float*)d_in[1];
  const float* c0 = (const float*)d_in[2];
  const float* Wi = (const float*)d_in[3];
  const float* Wh = (const float*)d_in[4];
  const float* bi = (const float*)d_in[5];
  const float* bh = (const float*)d_in[6];
  float* out = (float*)d_out;

  const size_t fixed = 262144 /*Wq*/ + 65536 /*c*/ + 16384 /*hq*/;
  int chunkT = 32;
  const int cands[4] = {256, 128, 64, 32};
  for (int i = 0; i < 4; ++i) {
    size_t slot = (size_t)cands[i] * 64 * 1024 * 4;  // fp32 bytes per slot
    if (fixed + 2 * slot <= ws_size) { chunkT = cands[i]; break; }
  }

  char* p = (char*)d_ws;
  signed char* Wq = (signed char*)p;  p += 262144;
  float* cst = (float*)p;             p += 65536;
  int* hqst = (int*)p;                p += 16384;
  float* ring = (float*)p;
  const size_t slotElems = (size_t)chunkT * 64 * 1024;

  quantw_kernel<<<1024, 256, 0, stream>>>(Wh, Wq);

  const int nchunks = 2048 / chunkT;
  for (int c = 0; c <= nchunks; ++c) {
    const int hg = (c < nchunks) ? 1 : 0;
    const int hr = (c > 0) ? 1 : 0;
    float* gs = ring + (size_t)(c & 1) * slotElems;
    const float* rs = ring + (size_t)((c ^ 1) & 1) * slotElems;
    const int ngb = hg ? (chunkT / 2) * 8 : 0;
    fused_kernel<<<64 + ngb, 512, 0, stream>>>(
        x, Wi, bi, bh, gs, (long)c * chunkT * 64, hg, rs, out, cst, hqst, h0,
        c0, Wq, (c - 1) * chunkT, chunkT, (c == 1) ? 1 : 0,
        (c == nchunks) ? 1 : 0, hr);
  }
}

// Round 4
// 1784.472 us; speedup vs baseline: 1.0919x; 1.0166x over previous
//
#include <hip/hip_runtime.h>

// subLSTM: T=2048, B=64, I=256, H=256, G=4H=1024.
// R10 = R9 with the step reordered to hide gi/go/prefetch inside the MFMA
// phase: [IO 16-MFMA block] {gi, t+2 prefetch, go} [FZ 16-MFMA block]
// {gf, gz, c-chain, sigm(c), hv, quant, stores}. The middle VALU issues
// while the OTHER wave on the SIMD feeds the MFMA pipe (separate pipes,
// barrier-synced phases overlap), so ~150cy leaves the serial tail.
// Hazard spacing: gi reads I (block1 issues 13/14), go reads O (15/16)
// after gi+prefetch ~65cy; gf reads F (block2 13/14) after SB; gz reads Z
// (15/16) after gf's ~35cy clause. All >= the ~24cy MFMA->VALU window.

typedef __attribute__((ext_vector_type(4))) float f32x4;
typedef __attribute__((ext_vector_type(8))) short bf16x8;
typedef __attribute__((ext_vector_type(4))) int i32x4;
typedef __attribute__((ext_vector_type(4))) unsigned short u16x4;

constexpr float WSCALE = 2032.0f;                 // 127 / 0.0625
constexpr float SC = 1.0f / (2032.0f * 127.0f);   // dequant

__device__ __forceinline__ unsigned short f2bf(float f) {
  unsigned u = __builtin_bit_cast(unsigned, f);
  u += 0x7fffu + ((u >> 16) & 1u);
  return (unsigned short)(u >> 16);
}
__device__ __forceinline__ float sigmf(float x) {
  return __builtin_amdgcn_rcpf(1.0f + __expf(-x));
}

// ---------------- W_h -> int8 ----------------
__global__ void quantw_kernel(const float* __restrict__ Wh,
                              signed char* __restrict__ Wq) {
  int i = blockIdx.x * 256 + threadIdx.x;
  float q = rintf(Wh[i] * WSCALE);
  q = fminf(127.0f, fmaxf(-127.0f, q));
  Wq[i] = (signed char)(int)q;
}

// ---------------- xproj GEMM body (proven 256-thr code; waves 4-7 idle
// but hit uniform __syncthreads) ----------------
__device__ __forceinline__ void gemm_body(char* smem, int gb,
                                          const float* __restrict__ x,
                                          const float* __restrict__ Wi,
                                          const float* __restrict__ bi,
                                          const float* __restrict__ bh,
                                          float* __restrict__ xpOut, long m0) {
  typedef unsigned short row72[72];
  row72* Al = (row72*)smem;
  row72* Bl = (row72*)(smem + 18432);
  const int tid = threadIdx.x;
  const int act = tid < 256;
  const int lane = tid & 63, wv = (tid >> 6) & 3;
  const int wm = wv >> 1, wn = wv & 1, cl = lane & 15, cg = lane >> 4;
  const int bx = gb >> 3, by = gb & 7;
  const long gm0 = m0 + (long)bx * 128;
  const int lm0 = bx * 128;
  const int n0 = by * 128;
  const int srow = (tid & 255) >> 1, sh = (tid & 1) * 32;

  f32x4 acc[4][4];
#pragma unroll
  for (int m = 0; m < 4; ++m)
#pragma unroll
    for (int n = 0; n < 4; ++n) acc[m][n] = (f32x4){0.f, 0.f, 0.f, 0.f};

  for (int kt = 0; kt < 4; ++kt) {
    if (act) {
      const float* pa = x + (gm0 + srow) * 256 + kt * 64 + sh;
      const float* pb = Wi + (long)(n0 + srow) * 256 + kt * 64 + sh;
#pragma unroll
      for (int j = 0; j < 8; ++j) {
        f32x4 va = *(const f32x4*)(pa + j * 4);
        f32x4 vb = *(const f32x4*)(pb + j * 4);
        u16x4 ua, ub;
#pragma unroll
        for (int k = 0; k < 4; ++k) { ua[k] = f2bf(va[k]); ub[k] = f2bf(vb[k]); }
        *(u16x4*)&Al[srow][sh + j * 4] = ua;
        *(u16x4*)&Bl[srow][sh + j * 4] = ub;
      }
    }
    __syncthreads();
    if (act) {
#pragma unroll
      for (int ks = 0; ks < 2; ++ks) {
        bf16x8 af[4], bfv[4];
#pragma unroll
        for (int m = 0; m < 4; ++m)
          af[m] = *(const bf16x8*)&Al[wm * 64 + m * 16 + cl][ks * 32 + cg * 8];
#pragma unroll
        for (int n = 0; n < 4; ++n)
          bfv[n] = *(const bf16x8*)&Bl[wn * 64 + n * 16 + cl][ks * 32 + cg * 8];
#pragma unroll
        for (int m = 0; m < 4; ++m)
#pragma unroll
          for (int n = 0; n < 4; ++n)
            acc[m][n] = __builtin_amdgcn_mfma_f32_16x16x32_bf16(
                af[m], bfv[n], acc[m][n], 0, 0, 0);
      }
    }
    __syncthreads();
  }
  if (act) {
#pragma unroll
    for (int n = 0; n < 4; ++n) {
      int gn = n0 + wn * 64 + n * 16 + cl;
      float bias = bi[gn] + bh[gn];
#pragma unroll
      for (int m = 0; m < 4; ++m) {
        int lrow = lm0 + wm * 64 + m * 16 + cg * 4;
#pragma unroll
        for (int r = 0; r < 4; ++r)
          xpOut[(long)(lrow + r) * 1024 + gn] = acc[m][n][r] + bias;
      }
    }
  }
}

// ---------------- recurrent body ----------------
#define SB() __builtin_amdgcn_sched_barrier(0)

#define RAW_BARRIER()                                         \
  do {                                                        \
    __builtin_amdgcn_sched_barrier(0);                        \
    asm volatile("s_waitcnt lgkmcnt(0)" ::: "memory");        \
    __builtin_amdgcn_s_barrier();                             \
    asm volatile("" ::: "memory");                            \
    __builtin_amdgcn_sched_barrier(0);                        \
  } while (0)

// 16 MFMAs, 4 independent accumulator chains (P-A0, P-A1, Q-A0, Q-A1)
// round-robin across the four K-quarters: same-chain spacing = 4 issue
// slots, so the block is issue-limited, not result-latency-limited.
// P chains finish at in-block issues 13/14, Q chains at 15/16.
#define MFMA_PAIR16(P0_, P1_, Q0_, Q1_, TP, TQ)                               \
  asm volatile("s_setprio 1\n\t"                                              \
               "s_nop 3\n\t"                                                  \
               "v_mfma_i32_16x16x64_i8 %0, %4, %20, %0\n\t"                   \
               "v_mfma_i32_16x16x64_i8 %1, %5, %20, %1\n\t"                   \
               "v_mfma_i32_16x16x64_i8 %2, %6, %20, %2\n\t"                   \
               "v_mfma_i32_16x16x64_i8 %3, %7, %20, %3\n\t"                   \
               "v_mfma_i32_16x16x64_i8 %0, %8, %21, %0\n\t"                   \
               "v_mfma_i32_16x16x64_i8 %1, %9, %21, %1\n\t"                   \
               "v_mfma_i32_16x16x64_i8 %2, %10, %21, %2\n\t"                  \
               "v_mfma_i32_16x16x64_i8 %3, %11, %21, %3\n\t"                  \
               "v_mfma_i32_16x16x64_i8 %0, %12, %22, %0\n\t"                  \
               "v_mfma_i32_16x16x64_i8 %1, %13, %22, %1\n\t"                  \
               "v_mfma_i32_16x16x64_i8 %2, %14, %22, %2\n\t"                  \
               "v_mfma_i32_16x16x64_i8 %3, %15, %22, %3\n\t"                  \
               "v_mfma_i32_16x16x64_i8 %0, %16, %23, %0\n\t"                  \
               "v_mfma_i32_16x16x64_i8 %1, %17, %23, %1\n\t"                  \
               "v_mfma_i32_16x16x64_i8 %2, %18, %23, %2\n\t"                  \
               "v_mfma_i32_16x16x64_i8 %3, %19, %23, %3\n\t"                  \
               "s_setprio 0"                                                  \
               : "+v"(P0_), "+v"(P1_), "+v"(Q0_), "+v"(Q1_)                   \
               : "a"(wf[TP][0][0]), "a"(wf[TP][1][0]), "a"(wf[TQ][0][0]),     \
                 "a"(wf[TQ][1][0]), "a"(wf[TP][0][1]), "a"(wf[TP][1][1]),     \
                 "a"(wf[TQ][0][1]), "a"(wf[TQ][1][1]), "a"(wf[TP][0][2]),     \
                 "a"(wf[TP][1][2]), "a"(wf[TQ][0][2]), "a"(wf[TQ][1][2]),     \
                 "a"(wf[TP][0][3]), "a"(wf[TP][1][3]), "a"(wf[TQ][0][3]),     \
                 "a"(wf[TQ][1][3]), "v"(bq0), "v"(bq1), "v"(bq2), "v"(bq3))

// select reg (cl&3) of chain ((cl>>2)&1) -- 7 cndmasks, masks loop-invariant
#define SEL8(A0_, A1_)                      \
  ({                                        \
    int t0_ = bs_ ? (A1_)[0] : (A0_)[0];    \
    int t1_ = bs_ ? (A1_)[1] : (A0_)[1];    \
    int t2_ = bs_ ? (A1_)[2] : (A0_)[2];    \
    int t3_ = bs_ ? (A1_)[3] : (A0_)[3];    \
    int lo_ = br0_ ? t1_ : t0_;             \
    int hi_ = br0_ ? t3_ : t2_;             \
    br1_ ? hi_ : lo_;                       \
  })

#define BQ_AND_ACC(TT)                                                         \
    const int rs = (TT) & 1;                                                   \
    i32x4 bq0 = *(const i32x4*)((const char*)(&hq[rs][0]) + 0 + cg * 16);      \
    i32x4 bq1 = *(const i32x4*)((const char*)(&hq[rs][0]) + 64 + cg * 16);     \
    i32x4 bq2 = *(const i32x4*)((const char*)(&hq[rs][0]) + 128 + cg * 16);    \
    i32x4 bq3 = *(const i32x4*)((const char*)(&hq[rs][0]) + 192 + cg * 16);    \
    i32x4 a00 = {0, 0, 0, 0}, a01 = {0, 0, 0, 0};                              \
    i32x4 a10 = {0, 0, 0, 0}, a11 = {0, 0, 0, 0};                              \
    i32x4 a20 = {0, 0, 0, 0}, a21 = {0, 0, 0, 0};                              \
    i32x4 a30 = {0, 0, 0, 0}, a31 = {0, 0, 0, 0};

#define STEP_TAIL(TT)                                                          \
    float hv = sc_ - go;                                                       \
    int qv = (int)rintf(hv * 127.0f);                                          \
    if (cl < 8) {                                                              \
      ((signed char*)(&hq[rs ^ 1][0]))[u] = (signed char)qv;                   \
      out[((long)(t0 + (TT)) * 64 + b) * 256 + u] = hv;                        \
      if (last && (TT) == nt - 1) {                                            \
        out[33554432L + b * 256 + u] = hv;                                     \
        out[33554432L + 16384L + b * 256 + u] = c_own;                         \
      }                                                                        \
    }                                                                          \
    RAW_BARRIER();

// Step: [IO block] {gi, prefetch, go} [FZ block] {gf, gz, c, sc_, tail}.
// gi/prefetch/go cost no MFMA pipe time (other wave feeds the pipe) and
// leave the serial tail. x-values for gf/gz/go saved before the prefetch
// overwrites XBUF with t+2 data.
#define STEP(TT, XBUF)                                                         \
  do {                                                                         \
    BQ_AND_ACC(TT)                                                             \
    MFMA_PAIR16(a00, a01, a10, a11, 0, 1); /* in + out (IO first) */           \
    SB();                                                                      \
    float x3s_ = XBUF[3], x2s_ = XBUF[2], x1s_ = XBUF[1];                      \
    float gi = sigmf(XBUF[0] + SC * (float)SEL8(a00, a01));                    \
    SB();                                                                      \
    if ((TT) + 2 < nt) { /* prefetch t+2; also spaces go from O writes */      \
      _Pragma("unroll") for (int tg = 0; tg < 4; ++tg)                         \
          XBUF[tg] = xp[((long)((TT) + 2) * 64 + b) * 1024 + tg * 256 + u];    \
    } else {                                                                   \
      asm volatile("s_nop 7\n\ts_nop 7");                                      \
    }                                                                          \
    SB();                                                                      \
    float go = sigmf(x1s_ + SC * (float)SEL8(a10, a11));                       \
    SB();                                                                      \
    MFMA_PAIR16(a30, a31, a20, a21, 3, 2); /* forget + z */                    \
    SB();                                                                      \
    float gf = sigmf(x3s_ + SC * (float)SEL8(a30, a31));                       \
    SB();                                                                      \
    float gz = sigmf(x2s_ + SC * (float)SEL8(a20, a21));                       \
    c_own = c_own * gf + gz - gi;                                              \
    float sc_ = sigmf(c_own);                                                  \
    STEP_TAIL(TT)                                                              \
  } while (0)

__device__ __forceinline__ void recur_body(
    char* smem, const float* __restrict__ xp, float* __restrict__ out,
    float* __restrict__ cst, int* __restrict__ hqst,
    const float* __restrict__ h0, const float* __restrict__ c0,
    const signed char* __restrict__ Wq, int t0, int nt, int first, int last) {
  const int b = blockIdx.x, tid = threadIdx.x;
  const int w = tid >> 6, lane = tid & 63, cl = lane & 15, cg = lane >> 4;
  const int bs_ = (cl >> 2) & 1;   // my s-chain
  const int br0_ = cl & 1;         // my reg r bit0
  const int br1_ = (cl >> 1) & 1;  // my reg r bit1
  const int u = w * 32 + bs_ * 16 + cg * 4 + (cl & 3);  // my ONE unit
  int(*hq)[64] = (int(*)[64])smem;  // int8 h, double-buffered (2x256B)

  // W_h fragments: rows tg*256 + w*32 + s*16 + cl, K chunk q*64 + cg*16.
  // Every use is via an "a" asm constraint -> pinned in 128 AGPRs.
  i32x4 wf[4][2][4];
#pragma unroll
  for (int tg = 0; tg < 4; ++tg)
#pragma unroll
    for (int s = 0; s < 2; ++s)
#pragma unroll
      for (int q = 0; q < 4; ++q)
        wf[tg][s][q] = *(const i32x4*)(Wq +
                                       (tg * 256 + w * 32 + s * 16 + cl) * 256 +
                                       q * 64 + cg * 16);

  float c_own = first ? c0[b * 256 + u] : cst[b * 256 + u];

  if (tid < 64) {
    int word;
    if (first) {
      int qj[4];
#pragma unroll
      for (int j = 0; j < 4; ++j) {
        float v = h0[b * 256 + tid * 4 + j];
        qj[j] = (int)rintf(fminf(1.0f, fmaxf(-1.0f, v)) * 127.0f);
      }
      word = (qj[0] & 255) | ((qj[1] & 255) << 8) | ((qj[2] & 255) << 16) |
             ((qj[3] & 255) << 24);
    } else {
      word = hqst[b * 64 + tid];
    }
    hq[0][tid] = word;
  }

  float xa[4], xb[4];
#pragma unroll
  for (int tg = 0; tg < 4; ++tg) {
    xa[tg] = xp[((long)0 * 64 + b) * 1024 + tg * 256 + u];
    xb[tg] = xp[((long)1 * 64 + b) * 1024 + tg * 256 + u];
  }
  __syncthreads();

  for (int t = 0; t < nt; t += 2) {
    STEP(t, xa);
    STEP(t + 1, xb);
  }

  if (cl < 8) cst[b * 256 + u] = c_own;
  if (tid < 64) hqst[b * 64 + tid] = hq[0][tid];
}

// ---------------- fused kernel ----------------
// blocks 0..63: recur chunk c-1.  blocks 64+: gemm chunk c.
// 82KB static smem -> hard 1 block/CU: gemm never co-resides with recur.
__global__ __launch_bounds__(512, 1) void fused_kernel(
    const float* __restrict__ x, const float* __restrict__ Wi,
    const float* __restrict__ bi, const float* __restrict__ bh,
    float* __restrict__ gslot, long m0, int have_gemm,
    const float* __restrict__ rslot, float* __restrict__ out,
    float* __restrict__ cst, int* __restrict__ hqst,
    const float* __restrict__ h0, const float* __restrict__ c0,
    const signed char* __restrict__ Wq, int t0, int nt, int first, int last,
    int have_recur) {
  __shared__ __align__(16) char smem[83968];
  if (blockIdx.x < 64) {
    if (have_recur)
      recur_body(smem, rslot, out, cst, hqst, h0, c0, Wq, t0, nt, first, last);
  } else {
    if (have_gemm) gemm_body(smem, blockIdx.x - 64, x, Wi, bi, bh, gslot, m0);
  }
}

// ---------------- host ----------------
extern "C" void kernel_launch(void* const* d_in, const int* in_sizes, int n_in,
                              void* d_out, int out_size, void* d_ws,
                              size_t ws_size, hipStream_t stream) {
  const float* x = (const float*)d_in[0];
  const float* h0 = (const float*)d_in[1];
  const float* c0 = (const float*)d_in[2];
  const float* Wi = (const float*)d_in[3];
  const float* Wh = (const float*)d_in[4];
  const float* bi = (const float*)d_in[5];
  const float* bh = (const float*)d_in[6];
  float* out = (float*)d_out;

  const size_t fixed = 262144 /*Wq*/ + 65536 /*c*/ + 16384 /*hq*/;
  int chunkT = 32;
  const int cands[4] = {256, 128, 64, 32};
  for (int i = 0; i < 4; ++i) {
    size_t slot = (size_t)cands[i] * 64 * 1024 * 4;  // fp32 bytes per slot
    if (fixed + 2 * slot <= ws_size) { chunkT = cands[i]; break; }
  }

  char* p = (char*)d_ws;
  signed char* Wq = (signed char*)p;  p += 262144;
  float* cst = (float*)p;             p += 65536;
  int* hqst = (int*)p;                p += 16384;
  float* ring = (float*)p;
  const size_t slotElems = (size_t)chunkT * 64 * 1024;

  quantw_kernel<<<1024, 256, 0, stream>>>(Wh, Wq);

  const int nchunks = 2048 / chunkT;
  for (int c = 0; c <= nchunks; ++c) {
    const int hg = (c < nchunks) ? 1 : 0;
    const int hr = (c > 0) ? 1 : 0;
    float* gs = ring + (size_t)(c & 1) * slotElems;
    const float* rs = ring + (size_t)((c ^ 1) & 1) * slotElems;
    const int ngb = hg ? (chunkT / 2) * 8 : 0;
    fused_kernel<<<64 + ngb, 512, 0, stream>>>(
        x, Wi, bi, bh, gs, (long)c * chunkT * 64, hg, rs, out, cst, hqst, h0,
        c0, Wq, (c - 1) * chunkT, chunkT, (c == 1) ? 1 : 0,
        (c == nchunks) ? 1 : 0, hr);
  }
}

// Round 5
// 1668.893 us; speedup vs baseline: 1.1676x; 1.0693x over previous
//
#include <hip/hip_runtime.h>

// subLSTM: T=2048, B=64, I=256, H=256, G=4H=1024.
// R11 = R10 with swapped MFMA operand roles in the recurrence:
//   old: D = A(W rows keyed cl) x B(h broadcast)  -> gate values spread over
//        the register dim -> 7-cndmask SEL8 per gate.
//   new: D = A(h broadcast rows) x B(W cols keyed cl) -> gate value for
//        W-row cl lands in D col=cl, REPLICATED across all 4 regs -> select
//        is ONE cndmask (s-group), unit map u = w*32 + (cg&1)*16 + cl,
//        dedup lane<32, contiguous 32-float out stores.
// Also: first MFMA of each chain uses src2 = persistent zero quad (zq) with
// early-clobber acc outputs -> the 32 per-step acc-zero v_movs vanish.
// Same math (A/B fragments share the lane->(idx,K) map: row/col=lane&15,
// K=(lane>>4)*16+byte; both halves proven by the R10 kernel's wiring).

typedef __attribute__((ext_vector_type(4))) float f32x4;
typedef __attribute__((ext_vector_type(8))) short bf16x8;
typedef __attribute__((ext_vector_type(4))) int i32x4;
typedef __attribute__((ext_vector_type(4))) unsigned short u16x4;

constexpr float WSCALE = 2032.0f;                 // 127 / 0.0625
constexpr float SC = 1.0f / (2032.0f * 127.0f);   // dequant

__device__ __forceinline__ unsigned short f2bf(float f) {
  unsigned u = __builtin_bit_cast(unsigned, f);
  u += 0x7fffu + ((u >> 16) & 1u);
  return (unsigned short)(u >> 16);
}
__device__ __forceinline__ float sigmf(float x) {
  return __builtin_amdgcn_rcpf(1.0f + __expf(-x));
}

// ---------------- W_h -> int8 ----------------
__global__ void quantw_kernel(const float* __restrict__ Wh,
                              signed char* __restrict__ Wq) {
  int i = blockIdx.x * 256 + threadIdx.x;
  float q = rintf(Wh[i] * WSCALE);
  q = fminf(127.0f, fmaxf(-127.0f, q));
  Wq[i] = (signed char)(int)q;
}

// ---------------- xproj GEMM body (proven 256-thr code; waves 4-7 idle
// but hit uniform __syncthreads) ----------------
__device__ __forceinline__ void gemm_body(char* smem, int gb,
                                          const float* __restrict__ x,
                                          const float* __restrict__ Wi,
                                          const float* __restrict__ bi,
                                          const float* __restrict__ bh,
                                          float* __restrict__ xpOut, long m0) {
  typedef unsigned short row72[72];
  row72* Al = (row72*)smem;
  row72* Bl = (row72*)(smem + 18432);
  const int tid = threadIdx.x;
  const int act = tid < 256;
  const int lane = tid & 63, wv = (tid >> 6) & 3;
  const int wm = wv >> 1, wn = wv & 1, cl = lane & 15, cg = lane >> 4;
  const int bx = gb >> 3, by = gb & 7;
  const long gm0 = m0 + (long)bx * 128;
  const int lm0 = bx * 128;
  const int n0 = by * 128;
  const int srow = (tid & 255) >> 1, sh = (tid & 1) * 32;

  f32x4 acc[4][4];
#pragma unroll
  for (int m = 0; m < 4; ++m)
#pragma unroll
    for (int n = 0; n < 4; ++n) acc[m][n] = (f32x4){0.f, 0.f, 0.f, 0.f};

  for (int kt = 0; kt < 4; ++kt) {
    if (act) {
      const float* pa = x + (gm0 + srow) * 256 + kt * 64 + sh;
      const float* pb = Wi + (long)(n0 + srow) * 256 + kt * 64 + sh;
#pragma unroll
      for (int j = 0; j < 8; ++j) {
        f32x4 va = *(const f32x4*)(pa + j * 4);
        f32x4 vb = *(const f32x4*)(pb + j * 4);
        u16x4 ua, ub;
#pragma unroll
        for (int k = 0; k < 4; ++k) { ua[k] = f2bf(va[k]); ub[k] = f2bf(vb[k]); }
        *(u16x4*)&Al[srow][sh + j * 4] = ua;
        *(u16x4*)&Bl[srow][sh + j * 4] = ub;
      }
    }
    __syncthreads();
    if (act) {
#pragma unroll
      for (int ks = 0; ks < 2; ++ks) {
        bf16x8 af[4], bfv[4];
#pragma unroll
        for (int m = 0; m < 4; ++m)
          af[m] = *(const bf16x8*)&Al[wm * 64 + m * 16 + cl][ks * 32 + cg * 8];
#pragma unroll
        for (int n = 0; n < 4; ++n)
          bfv[n] = *(const bf16x8*)&Bl[wn * 64 + n * 16 + cl][ks * 32 + cg * 8];
#pragma unroll
        for (int m = 0; m < 4; ++m)
#pragma unroll
          for (int n = 0; n < 4; ++n)
            acc[m][n] = __builtin_amdgcn_mfma_f32_16x16x32_bf16(
                af[m], bfv[n], acc[m][n], 0, 0, 0);
      }
    }
    __syncthreads();
  }
  if (act) {
#pragma unroll
    for (int n = 0; n < 4; ++n) {
      int gn = n0 + wn * 64 + n * 16 + cl;
      float bias = bi[gn] + bh[gn];
#pragma unroll
      for (int m = 0; m < 4; ++m) {
        int lrow = lm0 + wm * 64 + m * 16 + cg * 4;
#pragma unroll
        for (int r = 0; r < 4; ++r)
          xpOut[(long)(lrow + r) * 1024 + gn] = acc[m][n][r] + bias;
      }
    }
  }
}

// ---------------- recurrent body ----------------
#define SB() __builtin_amdgcn_sched_barrier(0)

#define RAW_BARRIER()                                         \
  do {                                                        \
    __builtin_amdgcn_sched_barrier(0);                        \
    asm volatile("s_waitcnt lgkmcnt(0)" ::: "memory");        \
    __builtin_amdgcn_s_barrier();                             \
    asm volatile("" ::: "memory");                            \
    __builtin_amdgcn_sched_barrier(0);                        \
  } while (0)

// 16 MFMAs, 4 independent accumulator chains (P0,P1,Q0,Q1) round-robin
// across the four K-quarters: same-chain spacing = 4 issue slots (issue-
// limited, not result-latency-limited). SWAPPED ROLES: A = bq (h broadcast,
// VGPR), B = wf (W cols keyed cl, AGPR). First round reads zq as src2 so
// the accs never need zero-init (outputs are early-clobber).
// P chains finish at in-block issues 13/14, Q chains at 15/16.
#define MFMA_PAIR16(P0_, P1_, Q0_, Q1_, TP, TQ)                               \
  asm volatile("s_setprio 1\n\t"                                              \
               "s_nop 3\n\t"                                                  \
               "v_mfma_i32_16x16x64_i8 %0, %20, %4, %24\n\t"                  \
               "v_mfma_i32_16x16x64_i8 %1, %20, %5, %24\n\t"                  \
               "v_mfma_i32_16x16x64_i8 %2, %20, %6, %24\n\t"                  \
               "v_mfma_i32_16x16x64_i8 %3, %20, %7, %24\n\t"                  \
               "v_mfma_i32_16x16x64_i8 %0, %21, %8, %0\n\t"                   \
               "v_mfma_i32_16x16x64_i8 %1, %21, %9, %1\n\t"                   \
               "v_mfma_i32_16x16x64_i8 %2, %21, %10, %2\n\t"                  \
               "v_mfma_i32_16x16x64_i8 %3, %21, %11, %3\n\t"                  \
               "v_mfma_i32_16x16x64_i8 %0, %22, %12, %0\n\t"                  \
               "v_mfma_i32_16x16x64_i8 %1, %22, %13, %1\n\t"                  \
               "v_mfma_i32_16x16x64_i8 %2, %22, %14, %2\n\t"                  \
               "v_mfma_i32_16x16x64_i8 %3, %22, %15, %3\n\t"                  \
               "v_mfma_i32_16x16x64_i8 %0, %23, %16, %0\n\t"                  \
               "v_mfma_i32_16x16x64_i8 %1, %23, %17, %1\n\t"                  \
               "v_mfma_i32_16x16x64_i8 %2, %23, %18, %2\n\t"                  \
               "v_mfma_i32_16x16x64_i8 %3, %23, %19, %3\n\t"                  \
               "s_setprio 0"                                                  \
               : "=&v"(P0_), "=&v"(P1_), "=&v"(Q0_), "=&v"(Q1_)               \
               : "a"(wf[TP][0][0]), "a"(wf[TP][1][0]), "a"(wf[TQ][0][0]),     \
                 "a"(wf[TQ][1][0]), "a"(wf[TP][0][1]), "a"(wf[TP][1][1]),     \
                 "a"(wf[TQ][0][1]), "a"(wf[TQ][1][1]), "a"(wf[TP][0][2]),     \
                 "a"(wf[TP][1][2]), "a"(wf[TQ][0][2]), "a"(wf[TQ][1][2]),     \
                 "a"(wf[TP][0][3]), "a"(wf[TP][1][3]), "a"(wf[TQ][0][3]),     \
                 "a"(wf[TQ][1][3]), "v"(bq0), "v"(bq1), "v"(bq2), "v"(bq3),   \
                 "v"(zq))

// gate value for this thread's unit: col=cl (any reg), pick s-chain by cg&1
#define SEL1(A0_, A1_) (bsel_ ? (A1_)[0] : (A0_)[0])

#define BQ_AND_ACC(TT)                                                         \
    const int rs = (TT) & 1;                                                   \
    i32x4 bq0 = *(const i32x4*)((const char*)(&hq[rs][0]) + 0 + cg * 16);      \
    i32x4 bq1 = *(const i32x4*)((const char*)(&hq[rs][0]) + 64 + cg * 16);     \
    i32x4 bq2 = *(const i32x4*)((const char*)(&hq[rs][0]) + 128 + cg * 16);    \
    i32x4 bq3 = *(const i32x4*)((const char*)(&hq[rs][0]) + 192 + cg * 16);    \
    i32x4 a00, a01, a10, a11, a20, a21, a30, a31;

#define STEP_TAIL(TT)                                                          \
    float hv = sc_ - go;                                                       \
    int qv = (int)rintf(hv * 127.0f);                                          \
    if (lane < 32) {                                                           \
      ((signed char*)(&hq[rs ^ 1][0]))[u] = (signed char)qv;                   \
      out[((long)(t0 + (TT)) * 64 + b) * 256 + u] = hv;                        \
      if (last && (TT) == nt - 1) {                                            \
        out[33554432L + b * 256 + u] = hv;                                     \
        out[33554432L + 16384L + b * 256 + u] = c_own;                         \
      }                                                                        \
    }                                                                          \
    RAW_BARRIER();

// Step: [IO block] {gi, prefetch, go} [FZ block] {gf, gz, c, sc_, tail}.
// gi/prefetch/go cost no MFMA pipe time (other wave feeds the pipe) and
// leave the serial tail. x-values for gf/gz/go saved before the prefetch
// overwrites XBUF with t+2 data.
#define STEP(TT, XBUF)                                                         \
  do {                                                                         \
    BQ_AND_ACC(TT)                                                             \
    MFMA_PAIR16(a00, a01, a10, a11, 0, 1); /* in + out (IO first) */           \
    SB();                                                                      \
    float x3s_ = XBUF[3], x2s_ = XBUF[2], x1s_ = XBUF[1];                      \
    float gi = sigmf(XBUF[0] + SC * (float)SEL1(a00, a01));                    \
    SB();                                                                      \
    if ((TT) + 2 < nt) { /* prefetch t+2; also spaces go from O writes */      \
      _Pragma("unroll") for (int tg = 0; tg < 4; ++tg)                         \
          XBUF[tg] = xp[((long)((TT) + 2) * 64 + b) * 1024 + tg * 256 + u];    \
    } else {                                                                   \
      asm volatile("s_nop 7\n\ts_nop 7");                                      \
    }                                                                          \
    SB();                                                                      \
    float go = sigmf(x1s_ + SC * (float)SEL1(a10, a11));                       \
    SB();                                                                      \
    MFMA_PAIR16(a30, a31, a20, a21, 3, 2); /* forget + z */                    \
    SB();                                                                      \
    float gf = sigmf(x3s_ + SC * (float)SEL1(a30, a31));                       \
    SB();                                                                      \
    float gz = sigmf(x2s_ + SC * (float)SEL1(a20, a21));                       \
    c_own = c_own * gf + gz - gi;                                              \
    float sc_ = sigmf(c_own);                                                  \
    STEP_TAIL(TT)                                                              \
  } while (0)

__device__ __forceinline__ void recur_body(
    char* smem, const float* __restrict__ xp, float* __restrict__ out,
    float* __restrict__ cst, int* __restrict__ hqst,
    const float* __restrict__ h0, const float* __restrict__ c0,
    const signed char* __restrict__ Wq, int t0, int nt, int first, int last) {
  const int b = blockIdx.x, tid = threadIdx.x;
  const int w = tid >> 6, lane = tid & 63, cl = lane & 15, cg = lane >> 4;
  const int bsel_ = cg & 1;                 // my s-chain
  const int u = w * 32 + bsel_ * 16 + cl;   // my ONE unit (lanes 0-31 own)
  int(*hq)[64] = (int(*)[64])smem;  // int8 h, double-buffered (2x256B)

  // W_h fragments: rows tg*256 + w*32 + s*16 + cl, K chunk q*64 + cg*16.
  // Used as the MFMA B operand (col = cl). Pinned in 128 AGPRs via "a".
  i32x4 wf[4][2][4];
#pragma unroll
  for (int tg = 0; tg < 4; ++tg)
#pragma unroll
    for (int s = 0; s < 2; ++s)
#pragma unroll
      for (int q = 0; q < 4; ++q)
        wf[tg][s][q] = *(const i32x4*)(Wq +
                                       (tg * 256 + w * 32 + s * 16 + cl) * 256 +
                                       q * 64 + cg * 16);

  const i32x4 zq = {0, 0, 0, 0};  // persistent zero quad (MFMA src2, round 0)

  float c_own = first ? c0[b * 256 + u] : cst[b * 256 + u];

  if (tid < 64) {
    int word;
    if (first) {
      int qj[4];
#pragma unroll
      for (int j = 0; j < 4; ++j) {
        float v = h0[b * 256 + tid * 4 + j];
        qj[j] = (int)rintf(fminf(1.0f, fmaxf(-1.0f, v)) * 127.0f);
      }
      word = (qj[0] & 255) | ((qj[1] & 255) << 8) | ((qj[2] & 255) << 16) |
             ((qj[3] & 255) << 24);
    } else {
      word = hqst[b * 64 + tid];
    }
    hq[0][tid] = word;
  }

  float xa[4], xb[4];
#pragma unroll
  for (int tg = 0; tg < 4; ++tg) {
    xa[tg] = xp[((long)0 * 64 + b) * 1024 + tg * 256 + u];
    xb[tg] = xp[((long)1 * 64 + b) * 1024 + tg * 256 + u];
  }
  __syncthreads();

  for (int t = 0; t < nt; t += 2) {
    STEP(t, xa);
    STEP(t + 1, xb);
  }

  if (lane < 32) cst[b * 256 + u] = c_own;
  if (tid < 64) hqst[b * 64 + tid] = hq[0][tid];
}

// ---------------- fused kernel ----------------
// blocks 0..63: recur chunk c-1.  blocks 64+: gemm chunk c.
// 82KB static smem -> hard 1 block/CU: gemm never co-resides with recur.
__global__ __launch_bounds__(512, 1) void fused_kernel(
    const float* __restrict__ x, const float* __restrict__ Wi,
    const float* __restrict__ bi, const float* __restrict__ bh,
    float* __restrict__ gslot, long m0, int have_gemm,
    const float* __restrict__ rslot, float* __restrict__ out,
    float* __restrict__ cst, int* __restrict__ hqst,
    const float* __restrict__ h0, const float* __restrict__ c0,
    const signed char* __restrict__ Wq, int t0, int nt, int first, int last,
    int have_recur) {
  __shared__ __align__(16) char smem[83968];
  if (blockIdx.x < 64) {
    if (have_recur)
      recur_body(smem, rslot, out, cst, hqst, h0, c0, Wq, t0, nt, first, last);
  } else {
    if (have_gemm) gemm_body(smem, blockIdx.x - 64, x, Wi, bi, bh, gslot, m0);
  }
}

// ---------------- host ----------------
extern "C" void kernel_launch(void* const* d_in, const int* in_sizes, int n_in,
                              void* d_out, int out_size, void* d_ws,
                              size_t ws_size, hipStream_t stream) {
  const float* x = (const float*)d_in[0];
  const float* h0 = (const float*)d_in[1];
  const float* c0 = (const float*)d_in[2];
  const float* Wi = (const float*)d_in[3];
  const float* Wh = (const float*)d_in[4];
  const float* bi = (const float*)d_in[5];
  const float* bh = (const float*)d_in[6];
  float* out = (float*)d_out;

  const size_t fixed = 262144 /*Wq*/ + 65536 /*c*/ + 16384 /*hq*/;
  int chunkT = 32;
  const int cands[4] = {256, 128, 64, 32};
  for (int i = 0; i < 4; ++i) {
    size_t slot = (size_t)cands[i] * 64 * 1024 * 4;  // fp32 bytes per slot
    if (fixed + 2 * slot <= ws_size) { chunkT = cands[i]; break; }
  }

  char* p = (char*)d_ws;
  signed char* Wq = (signed char*)p;  p += 262144;
  float* cst = (float*)p;             p += 65536;
  int* hqst = (int*)p;                p += 16384;
  float* ring = (float*)p;
  const size_t slotElems = (size_t)chunkT * 64 * 1024;

  quantw_kernel<<<1024, 256, 0, stream>>>(Wh, Wq);

  const int nchunks = 2048 / chunkT;
  for (int c = 0; c <= nchunks; ++c) {
    const int hg = (c < nchunks) ? 1 : 0;
    const int hr = (c > 0) ? 1 : 0;
    float* gs = ring + (size_t)(c & 1) * slotElems;
    const float* rs = ring + (size_t)((c ^ 1) & 1) * slotElems;
    const int ngb = hg ? (chunkT / 2) * 8 : 0;
    fused_kernel<<<64 + ngb, 512, 0, stream>>>(
        x, Wi, bi, bh, gs, (long)c * chunkT * 64, hg, rs, out, cst, hqst, h0,
        c0, Wq, (c - 1) * chunkT, chunkT, (c == 1) ? 1 : 0,
        (c == nchunks) ? 1 : 0, hr);
  }
}